// Round 1
// baseline (9513.276 us; speedup 1.0000x reference)
//
#include <hip/hip_runtime.h>
#include <cstddef>
#include <cstdint>

#define N_NODES 50000
#define N_EDGES 800000
#define D 64
#define EPS 1e-5f

__device__ __forceinline__ float leaky(float x){ return x > 0.f ? x : 0.2f*x; }

// =================== CSR build over dst ===================
__global__ void k_hist(const int* __restrict__ dst, int* __restrict__ counts, int m){
  int i = blockIdx.x*blockDim.x + threadIdx.x;
  if (i < m) atomicAdd(&counts[dst[i]], 1);
}

__global__ __launch_bounds__(1024) void k_scan(const int* __restrict__ counts,
                                               int* __restrict__ offs, int* __restrict__ cur, int n){
  __shared__ int buf[1024];
  __shared__ int carry;
  int t = threadIdx.x;
  if (t == 0) carry = 0;
  __syncthreads();
  for (int base = 0; base < n; base += 1024){
    int v = (base + t < n) ? counts[base + t] : 0;
    buf[t] = v;
    __syncthreads();
    for (int off = 1; off < 1024; off <<= 1){
      int x = buf[t];
      if (t >= off) x += buf[t - off];
      __syncthreads();
      buf[t] = x;
      __syncthreads();
    }
    int excl = buf[t] - v;
    int out = carry + excl;
    if (base + t < n){ offs[base+t] = out; cur[base+t] = out; }
    int tot = buf[1023];
    __syncthreads();
    if (t == 0) carry += tot;
    __syncthreads();
  }
  if (t == 0) offs[n] = carry;
}

__global__ void k_scatter(const int* __restrict__ dst, int* __restrict__ cur,
                          int* __restrict__ eid, int m){
  int i = blockIdx.x*blockDim.x + threadIdx.x;
  if (i < m){ int pos = atomicAdd(&cur[dst[i]], 1); eid[pos] = i; }
}

// =================== gated segment sum/max (per mixed_v input pair) ===================
__global__ __launch_bounds__(256) void k_gather_agg(const float* __restrict__ Vs, const float* __restrict__ Es,
                             const int* __restrict__ src, const int* __restrict__ offs,
                             const int* __restrict__ eid,
                             float* __restrict__ aggS, float* __restrict__ aggM){
  int lane = threadIdx.x & 63;
  int wave = (blockIdx.x*blockDim.x + threadIdx.x) >> 6;
  int nw = (gridDim.x*blockDim.x) >> 6;
  for (int n = wave; n < N_NODES; n += nw){
    int beg = offs[n], end = offs[n+1];
    float s = 0.f, mx = -3.4e38f;
    for (int i = beg; i < end; ++i){
      int e = eid[i];
      int sr = src[e];
      float es = Es[(size_t)e*D + lane];
      float g = 1.f/(1.f + __expf(-es));
      float msg = Vs[(size_t)sr*D + lane]*g;
      s += msg; mx = fmaxf(mx, msg);
    }
    aggS[(size_t)n*D + lane] = s;
    aggM[(size_t)n*D + lane] = (end > beg) ? mx : 0.f;   // empty segment -> 0 (isfinite replace)
  }
}

// =================== tiled GEMM machinery for mixed ops ===================
// LDS candidate tiles, TRANSPOSED (k-major): ct[c][k][row], 64 rows, stride 68 (16B aligned).
// A-reads are 16-lane broadcasts of float4 (conflict-free). W read from global (L1/L2 resident).
#define CT_STRIDE 68
#define CT_CAND   (64*CT_STRIDE)

// per-candidate 64x64 GEMM: out rows 4*tr.., cols 4*tc.. accumulated into acc[4][4]
__device__ __forceinline__ void gemm_cand64(const float* __restrict__ ctc,
                                            const float* __restrict__ Wc,
                                            int tr, int tc, float acc[4][4]){
  const float* ap = ctc + 4*tr;
  const float* wp = Wc + 4*tc;
  #pragma unroll 8
  for (int k = 0; k < 64; ++k){
    float4 a4 = *(const float4*)(ap + k*CT_STRIDE);   // ds_read_b128, broadcast
    float4 w4 = *(const float4*)(wp + (size_t)k*64);  // global dwordx4, cache-resident
    float av[4] = {a4.x, a4.y, a4.z, a4.w};
    float wv[4] = {w4.x, w4.y, w4.z, w4.w};
    #pragma unroll
    for (int rr = 0; rr < 4; ++rr){
      #pragma unroll
      for (int cc = 0; cc < 4; ++cc){
        acc[rr][cc] += av[rr]*wv[cc];
      }
    }
  }
}

// stage edge candidates: c0 = E, c1 = Vs[src]+Vs[dst]+E, c2 = Vs[src]*Vs[dst]
__device__ __forceinline__ void stage_cand_e(float* __restrict__ ct,
    const float* __restrict__ Vs, const float* __restrict__ Es,
    const int* __restrict__ src, const int* __restrict__ dst,
    int row0, int R, int t){
  int col4 = t & 15;          // float4 column group (k-group)
  int r0   = (t >> 4) * 4;    // 4 rows per thread
  float e[4][4], s[4][4], d[4][4];
  #pragma unroll
  for (int rr = 0; rr < 4; ++rr){
    int grow = row0 + r0 + rr;
    float4 e4 = make_float4(0.f,0.f,0.f,0.f), s4 = e4, d4 = e4;
    if (grow < R){
      int si = src[grow], di = dst[grow];
      e4 = *(const float4*)(Es + (size_t)grow*64 + col4*4);
      s4 = *(const float4*)(Vs + (size_t)si*64  + col4*4);
      d4 = *(const float4*)(Vs + (size_t)di*64  + col4*4);
    }
    e[rr][0]=e4.x; e[rr][1]=e4.y; e[rr][2]=e4.z; e[rr][3]=e4.w;
    s[rr][0]=s4.x; s[rr][1]=s4.y; s[rr][2]=s4.z; s[rr][3]=s4.w;
    d[rr][0]=d4.x; d[rr][1]=d4.y; d[rr][2]=d4.z; d[rr][3]=d4.w;
  }
  #pragma unroll
  for (int j = 0; j < 4; ++j){
    int k = col4*4 + j;
    float4 c0 = make_float4(e[0][j], e[1][j], e[2][j], e[3][j]);
    float4 c1 = make_float4(s[0][j]+d[0][j]+e[0][j], s[1][j]+d[1][j]+e[1][j],
                            s[2][j]+d[2][j]+e[2][j], s[3][j]+d[3][j]+e[3][j]);
    float4 c2 = make_float4(s[0][j]*d[0][j], s[1][j]*d[1][j],
                            s[2][j]*d[2][j], s[3][j]*d[3][j]);
    *(float4*)(ct + 0*CT_CAND + k*CT_STRIDE + r0) = c0;
    *(float4*)(ct + 1*CT_CAND + k*CT_STRIDE + r0) = c1;
    *(float4*)(ct + 2*CT_CAND + k*CT_STRIDE + r0) = c2;
  }
}

// stage node candidates: c0 = Vs, c1 = aggS, c2 = aggM (all row-contiguous)
__device__ __forceinline__ void stage_cand_v(float* __restrict__ ct,
    const float* __restrict__ Vs, const float* __restrict__ aggS, const float* __restrict__ aggM,
    int row0, int R, int t){
  int col4 = t & 15;
  int r0   = (t >> 4) * 4;
  float a[4][4], b[4][4], c[4][4];
  #pragma unroll
  for (int rr = 0; rr < 4; ++rr){
    int grow = row0 + r0 + rr;
    float4 v4 = make_float4(0.f,0.f,0.f,0.f), s4 = v4, m4 = v4;
    if (grow < R){
      v4 = *(const float4*)(Vs   + (size_t)grow*64 + col4*4);
      s4 = *(const float4*)(aggS + (size_t)grow*64 + col4*4);
      m4 = *(const float4*)(aggM + (size_t)grow*64 + col4*4);
    }
    a[rr][0]=v4.x; a[rr][1]=v4.y; a[rr][2]=v4.z; a[rr][3]=v4.w;
    b[rr][0]=s4.x; b[rr][1]=s4.y; b[rr][2]=s4.z; b[rr][3]=s4.w;
    c[rr][0]=m4.x; c[rr][1]=m4.y; c[rr][2]=m4.z; c[rr][3]=m4.w;
  }
  #pragma unroll
  for (int j = 0; j < 4; ++j){
    int k = col4*4 + j;
    *(float4*)(ct + 0*CT_CAND + k*CT_STRIDE + r0) =
        make_float4(a[0][j], a[1][j], a[2][j], a[3][j]);
    *(float4*)(ct + 1*CT_CAND + k*CT_STRIDE + r0) =
        make_float4(b[0][j], b[1][j], b[2][j], b[3][j]);
    *(float4*)(ct + 2*CT_CAND + k*CT_STRIDE + r0) =
        make_float4(c[0][j], c[1][j], c[2][j], c[3][j]);
  }
}

// stats epilogue: wave-reduce per-candidate col sums over the wave's 4 tr-groups, one atomic per wave
__device__ __forceinline__ void stats_reduce_atomic(float sreg[3][4], float qreg[3][4],
    float* __restrict__ statS, float* __restrict__ statQ, int t, int tc){
  #pragma unroll
  for (int c = 0; c < 3; ++c){
    #pragma unroll
    for (int cc = 0; cc < 4; ++cc){
      float s = sreg[c][cc], q = qreg[c][cc];
      s += __shfl_xor(s, 16); s += __shfl_xor(s, 32);
      q += __shfl_xor(q, 16); q += __shfl_xor(q, 32);
      if ((t & 63) < 16){
        atomicAdd(&statS[c*64 + tc*4 + cc], s);
        atomicAdd(&statQ[c*64 + tc*4 + cc], q);
      }
    }
  }
}

// =================== mixed_v: stats + apply ===================
__global__ __launch_bounds__(256,3) void k_stats_v2(const float* __restrict__ Vs,
    const float* __restrict__ aggS, const float* __restrict__ aggM,
    const float* __restrict__ W,
    float* __restrict__ statS, float* __restrict__ statQ, int R){
  __shared__ float ct[3*CT_CAND];
  int t = threadIdx.x;
  int tr = t >> 4, tc = t & 15;
  float sreg[3][4], qreg[3][4];
  #pragma unroll
  for (int c = 0; c < 3; ++c)
    #pragma unroll
    for (int cc = 0; cc < 4; ++cc){ sreg[c][cc] = 0.f; qreg[c][cc] = 0.f; }
  int ntiles = (R + 63) >> 6;
  for (int tile = blockIdx.x; tile < ntiles; tile += gridDim.x){
    __syncthreads();
    stage_cand_v(ct, Vs, aggS, aggM, tile << 6, R, t);
    __syncthreads();
    #pragma unroll
    for (int c = 0; c < 3; ++c){
      float acc[4][4];
      #pragma unroll
      for (int rr = 0; rr < 4; ++rr)
        #pragma unroll
        for (int cc = 0; cc < 4; ++cc) acc[rr][cc] = 0.f;
      gemm_cand64(ct + c*CT_CAND, W + (size_t)c*4096, tr, tc, acc);
      #pragma unroll
      for (int cc = 0; cc < 4; ++cc){
        float s = acc[0][cc]+acc[1][cc]+acc[2][cc]+acc[3][cc];
        float q = acc[0][cc]*acc[0][cc]+acc[1][cc]*acc[1][cc]
                + acc[2][cc]*acc[2][cc]+acc[3][cc]*acc[3][cc];
        sreg[c][cc] += s; qreg[c][cc] += q;
      }
    }
  }
  stats_reduce_atomic(sreg, qreg, statS, statQ, t, tc);
}

__global__ __launch_bounds__(256,3) void k_apply_v2(const float* __restrict__ Vs,
    const float* __restrict__ aggS, const float* __restrict__ aggM,
    const float* __restrict__ Wm, const float* __restrict__ bias,
    float* __restrict__ Out, int R, int accum){
  __shared__ float ct[3*CT_CAND];
  int t = threadIdx.x;
  int tr = t >> 4, tc = t & 15;
  float4 b4 = *(const float4*)(bias + 4*tc);
  int ntiles = (R + 63) >> 6;
  for (int tile = blockIdx.x; tile < ntiles; tile += gridDim.x){
    __syncthreads();
    stage_cand_v(ct, Vs, aggS, aggM, tile << 6, R, t);
    __syncthreads();
    float acc[4][4];
    #pragma unroll
    for (int rr = 0; rr < 4; ++rr)
      #pragma unroll
      for (int cc = 0; cc < 4; ++cc) acc[rr][cc] = 0.f;
    #pragma unroll
    for (int c = 0; c < 3; ++c)
      gemm_cand64(ct + c*CT_CAND, Wm + (size_t)c*4096, tr, tc, acc);
    int row0 = tile << 6;
    #pragma unroll
    for (int rr = 0; rr < 4; ++rr){
      int grow = row0 + 4*tr + rr;
      if (grow < R){
        float4 o = make_float4(acc[rr][0]+b4.x, acc[rr][1]+b4.y,
                               acc[rr][2]+b4.z, acc[rr][3]+b4.w);
        float* op = Out + (size_t)grow*64 + 4*tc;
        if (accum){ float4 p = *(const float4*)op; o.x+=p.x; o.y+=p.y; o.z+=p.z; o.w+=p.w; }
        *(float4*)op = o;
      }
    }
  }
}

// =================== mixed_e: stats + apply ===================
__global__ __launch_bounds__(256,3) void k_stats_e2(const float* __restrict__ Vs,
    const float* __restrict__ Es, const int* __restrict__ src, const int* __restrict__ dst,
    const float* __restrict__ W,
    float* __restrict__ statS, float* __restrict__ statQ, int R){
  __shared__ float ct[3*CT_CAND];
  int t = threadIdx.x;
  int tr = t >> 4, tc = t & 15;
  float sreg[3][4], qreg[3][4];
  #pragma unroll
  for (int c = 0; c < 3; ++c)
    #pragma unroll
    for (int cc = 0; cc < 4; ++cc){ sreg[c][cc] = 0.f; qreg[c][cc] = 0.f; }
  int ntiles = (R + 63) >> 6;
  for (int tile = blockIdx.x; tile < ntiles; tile += gridDim.x){
    __syncthreads();
    stage_cand_e(ct, Vs, Es, src, dst, tile << 6, R, t);
    __syncthreads();
    #pragma unroll
    for (int c = 0; c < 3; ++c){
      float acc[4][4];
      #pragma unroll
      for (int rr = 0; rr < 4; ++rr)
        #pragma unroll
        for (int cc = 0; cc < 4; ++cc) acc[rr][cc] = 0.f;
      gemm_cand64(ct + c*CT_CAND, W + (size_t)c*4096, tr, tc, acc);
      #pragma unroll
      for (int cc = 0; cc < 4; ++cc){
        float s = acc[0][cc]+acc[1][cc]+acc[2][cc]+acc[3][cc];
        float q = acc[0][cc]*acc[0][cc]+acc[1][cc]*acc[1][cc]
                + acc[2][cc]*acc[2][cc]+acc[3][cc]*acc[3][cc];
        sreg[c][cc] += s; qreg[c][cc] += q;
      }
    }
  }
  stats_reduce_atomic(sreg, qreg, statS, statQ, t, tc);
}

__global__ __launch_bounds__(256,3) void k_apply_e2(const float* __restrict__ Vs,
    const float* __restrict__ Es, const int* __restrict__ src, const int* __restrict__ dst,
    const float* __restrict__ Wm, const float* __restrict__ bias,
    float* __restrict__ Out, int R, int accum){
  __shared__ float ct[3*CT_CAND];
  int t = threadIdx.x;
  int tr = t >> 4, tc = t & 15;
  float4 b4 = *(const float4*)(bias + 4*tc);
  int ntiles = (R + 63) >> 6;
  for (int tile = blockIdx.x; tile < ntiles; tile += gridDim.x){
    __syncthreads();
    stage_cand_e(ct, Vs, Es, src, dst, tile << 6, R, t);
    __syncthreads();
    float acc[4][4];
    #pragma unroll
    for (int rr = 0; rr < 4; ++rr)
      #pragma unroll
      for (int cc = 0; cc < 4; ++cc) acc[rr][cc] = 0.f;
    #pragma unroll
    for (int c = 0; c < 3; ++c)
      gemm_cand64(ct + c*CT_CAND, Wm + (size_t)c*4096, tr, tc, acc);
    int row0 = tile << 6;
    #pragma unroll
    for (int rr = 0; rr < 4; ++rr){
      int grow = row0 + 4*tr + rr;
      if (grow < R){
        float4 o = make_float4(acc[rr][0]+b4.x, acc[rr][1]+b4.y,
                               acc[rr][2]+b4.z, acc[rr][3]+b4.w);
        float* op = Out + (size_t)grow*64 + 4*tc;
        if (accum){ float4 p = *(const float4*)op; o.x+=p.x; o.y+=p.y; o.z+=p.z; o.w+=p.w; }
        *(float4*)op = o;
      }
    }
  }
}

// =================== BN fold: softmax(w), alpha = p/sqrt(var+eps), Wm = W*alpha, bias ===================
__global__ __launch_bounds__(256) void k_finalize_mix(const float* __restrict__ statS, const float* __restrict__ statQ,
                               const float* __restrict__ arch, const float* __restrict__ W, float R,
                               float* __restrict__ Wm, float* __restrict__ biasOut){
  __shared__ float p[3];
  __shared__ float alpha[192], mm[192];
  int t = threadIdx.x;
  if (t == 0){
    float a0=arch[0], a1=arch[1], a2=arch[2];
    float mx = fmaxf(a0, fmaxf(a1,a2));
    float e0=__expf(a0-mx), e1=__expf(a1-mx), e2=__expf(a2-mx);
    float s = e0+e1+e2;
    p[0]=e0/s; p[1]=e1/s; p[2]=e2/s;
  }
  __syncthreads();
  if (t < 192){
    float m = statS[t]/R;
    float v = statQ[t]/R - m*m;
    float a = p[t>>6]/sqrtf(v + EPS);
    alpha[t] = a; mm[t] = m;
  }
  __syncthreads();
  if (t < 64){
    biasOut[t] = -(alpha[t]*mm[t] + alpha[64+t]*mm[64+t] + alpha[128+t]*mm[128+t]);
  }
  for (int idx = t; idx < 3*64*64; idx += 256){
    int i = idx >> 12;
    int j = idx & 63;
    Wm[idx] = W[idx]*alpha[i*64 + j];
  }
}

// =================== final MLP: tiled GEMM [64x128] over virtual cat, then @W2 ===================
__device__ __forceinline__ void stage_ct(float* ct, const float* __restrict__ Fp, int row0, int R, int t){
  #pragma unroll
  for (int it = 0; it < 4; ++it){
    int r  = it*16 + (t>>4);
    int c4 = (t&15)*4;
    float4 v = make_float4(0.f,0.f,0.f,0.f);
    int grow = row0 + r;
    if (grow < R) v = *(const float4*)(Fp + (size_t)grow*64 + c4);
    float* dp = ct + r*65 + c4;
    dp[0]=leaky(v.x); dp[1]=leaky(v.y); dp[2]=leaky(v.z); dp[3]=leaky(v.w);
  }
}
__device__ __forceinline__ void stage_wt(float* wt, const float* __restrict__ W1, int p, int t){
  #pragma unroll
  for (int it = 0; it < 8; ++it){
    int k  = it*8 + (t>>5);
    int c4 = (t&31)*4;
    *(float4*)(wt + k*128 + c4) = *(const float4*)(W1 + (size_t)(p*64 + k)*128 + c4);
  }
}
__device__ __forceinline__ void gemm1_k64(const float* ct, const float* wt, int tr, int tc, float acc[4][8]){
  for (int k = 0; k < 64; ++k){
    float a[4];
    #pragma unroll
    for (int rr=0;rr<4;++rr) a[rr] = ct[(4*tr+rr)*65 + k];
    const float* wk = wt + k*128 + 4*tc;
    float wl[4], wh[4];
    #pragma unroll
    for (int cc=0;cc<4;++cc){ wl[cc]=wk[cc]; wh[cc]=wk[64+cc]; }
    #pragma unroll
    for (int rr=0;rr<4;++rr){
      #pragma unroll
      for (int cc=0;cc<4;++cc){
        acc[rr][cc]   += a[rr]*wl[cc];
        acc[rr][4+cc] += a[rr]*wh[cc];
      }
    }
  }
}

__global__ __launch_bounds__(256) void k_mlp_stats(const float* __restrict__ F0, const float* __restrict__ F1,
                            const float* __restrict__ F2, const float* __restrict__ F3,
                            const float* __restrict__ W1,
                            float* __restrict__ statS, float* __restrict__ statQ, int R){
  __shared__ float ct[64*65];
  __shared__ float wt[64*128];
  __shared__ float cs[128], cq[128];
  int t = threadIdx.x;
  if (t < 128){ cs[t]=0.f; cq[t]=0.f; }
  int tr = t >> 4, tc = t & 15;
  int ntiles = (R + 63) >> 6;
  for (int tile = blockIdx.x; tile < ntiles; tile += gridDim.x){
    int row0 = tile << 6;
    float acc[4][8];
    #pragma unroll
    for (int rr=0;rr<4;++rr){
      #pragma unroll
      for (int cc=0;cc<8;++cc) acc[rr][cc]=0.f;
    }
    for (int p2 = 0; p2 < 4; ++p2){
      __syncthreads();
      const float* Fp = (p2==0)?F0:(p2==1)?F1:(p2==2)?F2:F3;
      stage_ct(ct, Fp, row0, R, t);
      stage_wt(wt, W1, p2, t);
      __syncthreads();
      gemm1_k64(ct, wt, tr, tc, acc);
    }
    #pragma unroll
    for (int cc=0;cc<4;++cc){
      float s1=0,q1=0,s2=0,q2=0;
      #pragma unroll
      for (int rr=0;rr<4;++rr){
        float x = acc[rr][cc];   s1+=x; q1+=x*x;
        float y = acc[rr][4+cc]; s2+=y; q2+=y*y;
      }
      atomicAdd(&cs[4*tc+cc], s1);    atomicAdd(&cq[4*tc+cc], q1);
      atomicAdd(&cs[64+4*tc+cc], s2); atomicAdd(&cq[64+4*tc+cc], q2);
    }
  }
  __syncthreads();
  if (t < 128){ atomicAdd(&statS[t], cs[t]); atomicAdd(&statQ[t], cq[t]); }
}

__global__ void k_mlp_finalize(const float* __restrict__ statS, const float* __restrict__ statQ,
                               float R, float* __restrict__ scale, float* __restrict__ biasb){
  int t = threadIdx.x;
  if (t < 128){
    float m = statS[t]/R;
    float v = statQ[t]/R - m*m;
    float s = 1.f/sqrtf(v + EPS);
    scale[t] = s;
    biasb[t] = -m*s;
  }
}

__global__ __launch_bounds__(256) void k_mlp_apply(const float* __restrict__ F0, const float* __restrict__ F1,
                           const float* __restrict__ F2, const float* __restrict__ F3,
                           const float* __restrict__ W1, const float* __restrict__ W2,
                           const float* __restrict__ scale, const float* __restrict__ biasb,
                           float* __restrict__ Out, int R){
  __shared__ float smem[64*65 + 64*128];   // ct+wt; reused as xt[64*129] after GEMM1
  float* ct = smem;
  float* wt = smem + 64*65;
  float* xt = smem;
  int t = threadIdx.x;
  int tr = t >> 4, tc = t & 15;
  // per-thread BN params for its 8 columns
  float scl[8], bsl[8];
  #pragma unroll
  for (int cc=0;cc<4;++cc){
    scl[cc]   = scale[4*tc+cc];    bsl[cc]   = biasb[4*tc+cc];
    scl[4+cc] = scale[64+4*tc+cc]; bsl[4+cc] = biasb[64+4*tc+cc];
  }
  int ntiles = (R + 63) >> 6;
  for (int tile = blockIdx.x; tile < ntiles; tile += gridDim.x){
    int row0 = tile << 6;
    float acc[4][8];
    #pragma unroll
    for (int rr=0;rr<4;++rr){
      #pragma unroll
      for (int cc=0;cc<8;++cc) acc[rr][cc]=0.f;
    }
    for (int p2 = 0; p2 < 4; ++p2){
      __syncthreads();                         // protects xt (aliases ct/wt) of prev tile + prev stage
      const float* Fp = (p2==0)?F0:(p2==1)?F1:(p2==2)?F2:F3;
      stage_ct(ct, Fp, row0, R, t);
      stage_wt(wt, W1, p2, t);
      __syncthreads();
      gemm1_k64(ct, wt, tr, tc, acc);
    }
    __syncthreads();                           // all GEMM1 reads done before xt overwrite
    #pragma unroll
    for (int rr=0;rr<4;++rr){
      int r = 4*tr + rr;
      #pragma unroll
      for (int cc=0;cc<4;++cc){
        float xl = acc[rr][cc]*scl[cc] + bsl[cc];
        float xh = acc[rr][4+cc]*scl[4+cc] + bsl[4+cc];
        xt[r*129 + 4*tc+cc]      = leaky(xl);
        xt[r*129 + 64 + 4*tc+cc] = leaky(xh);
      }
    }
    __syncthreads();
    // GEMM2: [64x128] @ W2[128x64]
    float acc2[4][4];
    #pragma unroll
    for (int rr=0;rr<4;++rr){
      #pragma unroll
      for (int cc=0;cc<4;++cc) acc2[rr][cc]=0.f;
    }
    for (int k = 0; k < 128; ++k){
      float a2[4];
      #pragma unroll
      for (int rr=0;rr<4;++rr) a2[rr] = xt[(4*tr+rr)*129 + k];
      float4 w2 = *(const float4*)(W2 + (size_t)k*64 + 4*tc);
      #pragma unroll
      for (int rr=0;rr<4;++rr){
        acc2[rr][0] += a2[rr]*w2.x; acc2[rr][1] += a2[rr]*w2.y;
        acc2[rr][2] += a2[rr]*w2.z; acc2[rr][3] += a2[rr]*w2.w;
      }
    }
    #pragma unroll
    for (int rr=0;rr<4;++rr){
      int r = row0 + 4*tr + rr;
      if (r < R)
        *(float4*)(Out + (size_t)r*64 + 4*tc) =
            make_float4(acc2[rr][0], acc2[rr][1], acc2[rr][2], acc2[rr][3]);
    }
  }
}

// =================== host orchestration ===================
extern "C" void kernel_launch(void* const* d_in, const int* in_sizes, int n_in,
                              void* d_out, int out_size, void* d_ws, size_t ws_size,
                              hipStream_t stream){
  (void)in_sizes; (void)n_in; (void)out_size; (void)ws_size;
  const float* V0  = (const float*)d_in[0];
  const float* V1  = (const float*)d_in[1];
  const float* E0  = (const float*)d_in[2];
  const float* E1  = (const float*)d_in[3];
  const int*   src = (const int*)d_in[4];
  const int*   dst = (const int*)d_in[5];
  const float* arch= (const float*)d_in[6];
  const float* Wv  = (const float*)d_in[7];
  const float* We  = (const float*)d_in[8];
  const float* Wv1 = (const float*)d_in[9];
  const float* Wv2 = (const float*)d_in[10];
  const float* We1 = (const float*)d_in[11];
  const float* We2 = (const float*)d_in[12];
  float* outV = (float*)d_out;
  float* outE = (float*)d_out + (size_t)N_NODES*D;

  char* wsB = (char*)d_ws; size_t off = 0;
  auto carve = [&](size_t bytes)->void*{
    void* p = wsB + off; off += (bytes + 255) & ~((size_t)255); return p;
  };
  float* V2    = (float*)carve((size_t)N_NODES*D*sizeof(float));
  float* E2    = (float*)carve((size_t)N_EDGES*D*sizeof(float));
  float* aggS  = (float*)carve((size_t)N_NODES*D*sizeof(float));
  float* aggM  = (float*)carve((size_t)N_NODES*D*sizeof(float));
  int*   counts= (int*)carve((size_t)N_NODES*sizeof(int));
  int*   offs  = (int*)carve((size_t)(N_NODES+1)*sizeof(int));
  int*   cur   = (int*)carve((size_t)N_NODES*sizeof(int));
  int*   eid   = (int*)carve((size_t)N_EDGES*sizeof(int));
  float* statS = (float*)carve(384*sizeof(float));
  float* statQ = (float*)carve(384*sizeof(float));
  float* Wm    = (float*)carve((size_t)3*64*64*sizeof(float));
  float* biasM = (float*)carve(64*sizeof(float));
  float* mScale= (float*)carve(128*sizeof(float));
  float* mBias = (float*)carve(128*sizeof(float));

  float* V3 = outV;   // alias d_out (per-tile read-before-write in mlp_apply is safe)
  float* E3 = outE;

  // CSR over dst (shared by all mixed_v aggregations)
  hipMemsetAsync(counts, 0, (size_t)N_NODES*sizeof(int), stream);
  k_hist<<<(N_EDGES+255)/256, 256, 0, stream>>>(dst, counts, N_EDGES);
  k_scan<<<1, 1024, 0, stream>>>(counts, offs, cur, N_NODES);
  k_scatter<<<(N_EDGES+255)/256, 256, 0, stream>>>(dst, cur, eid, N_EDGES);

  auto run_mixed_v = [&](const float* Vs, const float* Es, int lv, float* Outp, int accum, bool gather){
    if (gather) k_gather_agg<<<512,256,0,stream>>>(Vs, Es, src, offs, eid, aggS, aggM);
    hipMemsetAsync(statS, 0, 384*sizeof(float), stream);
    hipMemsetAsync(statQ, 0, 384*sizeof(float), stream);
    k_stats_v2<<<768,256,0,stream>>>(Vs, aggS, aggM, Wv + (size_t)lv*12288, statS, statQ, N_NODES);
    k_finalize_mix<<<1,256,0,stream>>>(statS, statQ, arch + lv*3, Wv + (size_t)lv*12288,
                                       (float)N_NODES, Wm, biasM);
    k_apply_v2<<<768,256,0,stream>>>(Vs, aggS, aggM, Wm, biasM, Outp, N_NODES, accum);
  };
  auto run_mixed_e = [&](const float* Vs, const float* Es, int le, float* Outp, int accum){
    hipMemsetAsync(statS, 0, 384*sizeof(float), stream);
    hipMemsetAsync(statQ, 0, 384*sizeof(float), stream);
    k_stats_e2<<<768,256,0,stream>>>(Vs, Es, src, dst, We + (size_t)le*12288, statS, statQ, N_EDGES);
    k_finalize_mix<<<1,256,0,stream>>>(statS, statQ, arch + (4+le)*3, We + (size_t)le*12288,
                                       (float)N_EDGES, Wm, biasM);
    k_apply_e2<<<768,256,0,stream>>>(Vs, Es, src, dst, Wm, biasM, Outp, N_EDGES, accum);
  };

  // state 2
  run_mixed_v(V0, E0, 0, V2, 0, true);
  run_mixed_v(V1, E1, 1, V2, 1, true);
  run_mixed_e(V0, E0, 0, E2, 0);
  run_mixed_e(V1, E1, 1, E2, 1);
  // state 3
  run_mixed_v(V1, E1, 2, V3, 0, false);   // agg(V1,E1) still valid from lv=1
  run_mixed_v(V2, E2, 3, V3, 1, true);
  run_mixed_e(V1, E1, 2, E3, 0);
  run_mixed_e(V2, E2, 3, E3, 1);

  // final V MLP
  hipMemsetAsync(statS, 0, 384*sizeof(float), stream);
  hipMemsetAsync(statQ, 0, 384*sizeof(float), stream);
  k_mlp_stats<<<768,256,0,stream>>>(V0, V1, V2, V3, Wv1, statS, statQ, N_NODES);
  k_mlp_finalize<<<1,128,0,stream>>>(statS, statQ, (float)N_NODES, mScale, mBias);
  k_mlp_apply<<<768,256,0,stream>>>(V0, V1, V2, V3, Wv1, Wv2, mScale, mBias, outV, N_NODES);

  // final E MLP
  hipMemsetAsync(statS, 0, 384*sizeof(float), stream);
  hipMemsetAsync(statQ, 0, 384*sizeof(float), stream);
  k_mlp_stats<<<768,256,0,stream>>>(E0, E1, E2, E3, We1, statS, statQ, N_EDGES);
  k_mlp_finalize<<<1,128,0,stream>>>(statS, statQ, (float)N_EDGES, mScale, mBias);
  k_mlp_apply<<<768,256,0,stream>>>(E0, E1, E2, E3, We1, We2, mScale, mBias, outE, N_EDGES);
}